// Round 7
// baseline (262.361 us; speedup 1.0000x reference)
//
#include <hip/hip_runtime.h>

typedef unsigned short u16;
typedef unsigned int   u32;
typedef float f32x4  __attribute__((ext_vector_type(4)));
typedef short bf16x8 __attribute__((ext_vector_type(8)));

__device__ __forceinline__ u16 f2b_rne(float x) {
    u32 u = __float_as_uint(x);
    return (u16)((u + 0x7fffu + ((u >> 16) & 1u)) >> 16);
}
__device__ __forceinline__ float b2f(u16 u) { return __uint_as_float((u32)u << 16); }
__device__ __forceinline__ void split1(float x, u16& h, u16& l) {
    h = f2b_rne(x);
    l = f2b_rne(x - b2f(h));
}
__device__ __forceinline__ void mk_frag(f32x4 a, f32x4 b, bf16x8& hi, bf16x8& lo) {
#pragma unroll
    for (int j = 0; j < 4; ++j) { u16 h, l; split1(a[j], h, l); hi[j] = (short)h; lo[j] = (short)l; }
#pragma unroll
    for (int j = 0; j < 4; ++j) { u16 h, l; split1(b[j], h, l); hi[4+j] = (short)h; lo[4+j] = (short)l; }
}

// ---------------------------------------------------------------------------
// kemb_mfma (cand): ec[M x 64](fp32) = X @ We^T + be, split-bf16 MFMA.
// Verbatim from rounds 5/6 (proven PASS @ absmax 2e-3).
// ---------------------------------------------------------------------------
__global__ __launch_bounds__(256) void kemb_mfma(
    const float* __restrict__ X, const float* __restrict__ W, const float* __restrict__ be,
    float* __restrict__ out, int M)
{
    const int wv   = threadIdx.x >> 6;
    const int lane = threadIdx.x & 63;
    const int l15  = lane & 15;
    const int q    = lane >> 4;

    const int arow = min(blockIdx.x * 16 + l15, M - 1);
    const float* xr = X + (size_t)arow * 1000;
    const float* wr = W + (size_t)(wv * 16 + l15) * 1000;

    const float bias = be[wv * 16 + l15];
    f32x4 acc = {bias, bias, bias, bias};

    for (int kc = 0; kc < 992; kc += 32) {
        bf16x8 ah, al, bh, bl;
        mk_frag(*(const f32x4*)(xr + kc + q * 8), *(const f32x4*)(xr + kc + q * 8 + 4), ah, al);
        mk_frag(*(const f32x4*)(wr + kc + q * 8), *(const f32x4*)(wr + kc + q * 8 + 4), bh, bl);
        acc = __builtin_amdgcn_mfma_f32_16x16x32_bf16(ah, bh, acc, 0, 0, 0);
        acc = __builtin_amdgcn_mfma_f32_16x16x32_bf16(ah, bl, acc, 0, 0, 0);
        acc = __builtin_amdgcn_mfma_f32_16x16x32_bf16(al, bh, acc, 0, 0, 0);
    }
    {
        bf16x8 ah = {0,0,0,0,0,0,0,0}, al = {0,0,0,0,0,0,0,0};
        bf16x8 bh = {0,0,0,0,0,0,0,0}, bl = {0,0,0,0,0,0,0,0};
        if (q == 0) {
            mk_frag(*(const f32x4*)(xr + 992), *(const f32x4*)(xr + 996), ah, al);
            mk_frag(*(const f32x4*)(wr + 992), *(const f32x4*)(wr + 996), bh, bl);
        }
        acc = __builtin_amdgcn_mfma_f32_16x16x32_bf16(ah, bh, acc, 0, 0, 0);
        acc = __builtin_amdgcn_mfma_f32_16x16x32_bf16(ah, bl, acc, 0, 0, 0);
        acc = __builtin_amdgcn_mfma_f32_16x16x32_bf16(al, bh, acc, 0, 0, 0);
    }
#pragma unroll
    for (int r = 0; r < 4; ++r) {
        int m = blockIdx.x * 16 + q * 4 + r;
        if (m < M) out[(size_t)m * 64 + wv * 16 + l15] = acc[r];
    }
}

// ---------------------------------------------------------------------------
// kemb_rated: GEMM for rated (M=1000); emits er_t (transposed split-bf16)
// and ar via in-kernel MFMA. Verbatim from round 6 (proven).
// ---------------------------------------------------------------------------
__global__ __launch_bounds__(256) void kemb_rated(
    const float* __restrict__ X, const float* __restrict__ W, const float* __restrict__ be,
    const float* __restrict__ Wa1,
    u16* __restrict__ er_th, u16* __restrict__ er_tl, float* __restrict__ ar)
{
    __shared__ float smt[16 * 68];
    const int wv   = threadIdx.x >> 6;
    const int lane = threadIdx.x & 63;
    const int l15  = lane & 15;
    const int q    = lane >> 4;
    const int i0   = blockIdx.x * 16;

    const int arow = min(i0 + l15, 999);
    const float* xr = X + (size_t)arow * 1000;
    const float* wr = W + (size_t)(wv * 16 + l15) * 1000;

    const float bias = be[wv * 16 + l15];
    f32x4 acc = {bias, bias, bias, bias};

    for (int kc = 0; kc < 992; kc += 32) {
        bf16x8 ah, al, bh, bl;
        mk_frag(*(const f32x4*)(xr + kc + q * 8), *(const f32x4*)(xr + kc + q * 8 + 4), ah, al);
        mk_frag(*(const f32x4*)(wr + kc + q * 8), *(const f32x4*)(wr + kc + q * 8 + 4), bh, bl);
        acc = __builtin_amdgcn_mfma_f32_16x16x32_bf16(ah, bh, acc, 0, 0, 0);
        acc = __builtin_amdgcn_mfma_f32_16x16x32_bf16(ah, bl, acc, 0, 0, 0);
        acc = __builtin_amdgcn_mfma_f32_16x16x32_bf16(al, bh, acc, 0, 0, 0);
    }
    {
        bf16x8 ah = {0,0,0,0,0,0,0,0}, al = {0,0,0,0,0,0,0,0};
        bf16x8 bh = {0,0,0,0,0,0,0,0}, bl = {0,0,0,0,0,0,0,0};
        if (q == 0) {
            mk_frag(*(const f32x4*)(xr + 992), *(const f32x4*)(xr + 996), ah, al);
            mk_frag(*(const f32x4*)(wr + 992), *(const f32x4*)(wr + 996), bh, bl);
        }
        acc = __builtin_amdgcn_mfma_f32_16x16x32_bf16(ah, bh, acc, 0, 0, 0);
        acc = __builtin_amdgcn_mfma_f32_16x16x32_bf16(ah, bl, acc, 0, 0, 0);
        acc = __builtin_amdgcn_mfma_f32_16x16x32_bf16(al, bh, acc, 0, 0, 0);
    }

    const int e = wv * 16 + l15;
#pragma unroll
    for (int r = 0; r < 4; ++r) {
        int i = i0 + q * 4 + r;
        smt[(q * 4 + r) * 68 + e] = acc[r];
        if (i < 1000) {
            u16 h, l; split1(acc[r], h, l);
            er_th[(size_t)e * 1000 + i] = h;
            er_tl[(size_t)e * 1000 + i] = l;
        }
    }
    __syncthreads();

    if (wv == 0) {
        f32x4 a2 = {0.f, 0.f, 0.f, 0.f};
#pragma unroll
        for (int kc = 0; kc < 64; kc += 32) {
            const float* ap = smt + l15 * 68 + kc + q * 8;
            const float* bp = Wa1 + l15 * 128 + 64 + kc + q * 8;
            bf16x8 ah, al, bh, bl;
            mk_frag(*(const f32x4*)ap, *(const f32x4*)(ap + 4), ah, al);
            mk_frag(*(const f32x4*)bp, *(const f32x4*)(bp + 4), bh, bl);
            a2 = __builtin_amdgcn_mfma_f32_16x16x32_bf16(ah, bh, a2, 0, 0, 0);
            a2 = __builtin_amdgcn_mfma_f32_16x16x32_bf16(ah, bl, a2, 0, 0, 0);
            a2 = __builtin_amdgcn_mfma_f32_16x16x32_bf16(al, bh, a2, 0, 0, 0);
        }
#pragma unroll
        for (int r = 0; r < 4; ++r) {
            int i = i0 + q * 4 + r;
            if (i < 1000) ar[(size_t)i * 16 + l15] = a2[r];
        }
    }
}

// ---------------------------------------------------------------------------
// k3v7: 4 batch rows per block (vs 8) -> LDS 16.3 KB -> 8 blocks/CU = 32
// waves/CU (was 4 blk / 16 waves @ 42% occ). Theory: round-6's 89 us was
// ~60 us latency stall; 2x resident waves + 7 barriers (was 12) hides it.
// LDS: sc[4][1000] u32 (scores -> packed split-bf16 P in place), smf:
// ACL[4][16] @0, SUMS[4] @64. Overlay after P2: XB[4][128] @0, H1[4][64]
// @512, H2[4][32] @768. Softmax & MLP are wave-local (b = wave id).
// ---------------------------------------------------------------------------
__global__ __launch_bounds__(256) void k3v7(
    const float* __restrict__ ar, const float* __restrict__ ecC,
    const u16* __restrict__ er_th, const u16* __restrict__ er_tl,
    const float* __restrict__ um, const float* __restrict__ Wa1, const float* __restrict__ ba1,
    const float* __restrict__ Wa2,
    const float* __restrict__ Wm1, const float* __restrict__ bm1,
    const float* __restrict__ Wm2, const float* __restrict__ bm2,
    const float* __restrict__ Wm3, const float* __restrict__ bm3,
    float* __restrict__ out)
{
    __shared__ u32   sc[4000];
    __shared__ float smf[72];
    float* xb = (float*)sc;
    const int t  = threadIdx.x;
    const int b0 = blockIdx.x * 4;

    // ACL[b][a] = ba1[a] + ec[b0+b] . W1c[a]   (ec read direct from L2)
    if (t < 64) {
        const int b = t & 3, a = t >> 2;
        float acc = ba1[a];
        const float* ecr = ecC + (size_t)(b0 + b) * 64;
        const float* w = Wa1 + a * 128;
#pragma unroll 8
        for (int e = 0; e < 64; ++e) acc += ecr[e] * w[e];
        smf[b * 16 + a] = acc;
    }
    __syncthreads();

    // P1: sc[b][i] = sum_a relu(ACL[b][a] + ar[i][a]) * Wa2[a]
    {
        const int b = t & 3, c = t >> 2;          // c in [0,64)
        float acb[16], w2[16];
#pragma unroll
        for (int a = 0; a < 16; ++a) acb[a] = smf[b * 16 + a];
#pragma unroll
        for (int a = 0; a < 16; ++a) w2[a] = Wa2[a];
        for (int j = 0; j < 16; ++j) {
            int i = c + 64 * j;
            if (i >= 1000) break;
            const f32x4* a4 = (const f32x4*)(ar + (size_t)i * 16);
            f32x4 r0 = a4[0], r1 = a4[1], r2 = a4[2], r3 = a4[3];
            float s = 0.f;
            s += fmaxf(acb[0]  + r0[0], 0.f) * w2[0];
            s += fmaxf(acb[1]  + r0[1], 0.f) * w2[1];
            s += fmaxf(acb[2]  + r0[2], 0.f) * w2[2];
            s += fmaxf(acb[3]  + r0[3], 0.f) * w2[3];
            s += fmaxf(acb[4]  + r1[0], 0.f) * w2[4];
            s += fmaxf(acb[5]  + r1[1], 0.f) * w2[5];
            s += fmaxf(acb[6]  + r1[2], 0.f) * w2[6];
            s += fmaxf(acb[7]  + r1[3], 0.f) * w2[7];
            s += fmaxf(acb[8]  + r2[0], 0.f) * w2[8];
            s += fmaxf(acb[9]  + r2[1], 0.f) * w2[9];
            s += fmaxf(acb[10] + r2[2], 0.f) * w2[10];
            s += fmaxf(acb[11] + r2[3], 0.f) * w2[11];
            s += fmaxf(acb[12] + r3[0], 0.f) * w2[12];
            s += fmaxf(acb[13] + r3[1], 0.f) * w2[13];
            s += fmaxf(acb[14] + r3[2], 0.f) * w2[14];
            s += fmaxf(acb[15] + r3[3], 0.f) * w2[15];
            sc[b * 1000 + i] = __float_as_uint(s);
        }
    }
    __syncthreads();

    // softmax (wave-local: b = wave id); pack P = exp(s-m)*um split-bf16 in place
    {
        const int b = t >> 6, g = t & 63;
        float m = -1e30f;
        for (int i = g; i < 1000; i += 64) m = fmaxf(m, __uint_as_float(sc[b * 1000 + i]));
#pragma unroll
        for (int k = 1; k < 64; k <<= 1) m = fmaxf(m, __shfl_xor(m, k));
        float sum = 0.f;
        const float* umr = um + (size_t)(b0 + b) * 1000;
        for (int i = g; i < 1000; i += 64) {
            float w = __expf(__uint_as_float(sc[b * 1000 + i]) - m);
            sum += w;
            float p = w * umr[i];
            u16 h, l; split1(p, h, l);
            sc[b * 1000 + i] = (u32)h | ((u32)l << 16);
        }
#pragma unroll
        for (int k = 1; k < 64; k <<= 1) sum += __shfl_xor(sum, k);
        if (g == 0) smf[64 + b] = 1.0f / sum;
    }
    __syncthreads();

    // P2: user_emb via MFMA. A rows mirror score rows (m -> m&3); wave = e-tile.
    {
        const int wv = t >> 6, lane = t & 63, l15 = lane & 15, q = lane >> 4;
        const int mb = l15 & 3;
        const u16* bhp = er_th + (size_t)(wv * 16 + l15) * 1000;
        const u16* blp = er_tl + (size_t)(wv * 16 + l15) * 1000;
        f32x4 acc = {0.f, 0.f, 0.f, 0.f};

        for (int kc = 0; kc < 992; kc += 32) {
            const u32* ap = sc + mb * 1000 + kc + q * 8;
            u32 pw[8];
            *(uint4*)(pw)     = *(const uint4*)(ap);
            *(uint4*)(pw + 4) = *(const uint4*)(ap + 4);
            bf16x8 ah, al;
#pragma unroll
            for (int j = 0; j < 8; ++j) {
                ah[j] = (short)(pw[j] & 0xffffu);
                al[j] = (short)(pw[j] >> 16);
            }
            bf16x8 bh = *(const bf16x8*)(bhp + kc + q * 8);
            bf16x8 bl = *(const bf16x8*)(blp + kc + q * 8);
            acc = __builtin_amdgcn_mfma_f32_16x16x32_bf16(ah, bh, acc, 0, 0, 0);
            acc = __builtin_amdgcn_mfma_f32_16x16x32_bf16(ah, bl, acc, 0, 0, 0);
            acc = __builtin_amdgcn_mfma_f32_16x16x32_bf16(al, bh, acc, 0, 0, 0);
        }
        {   // K tail 992..999 (q==0 only)
            u32 pw[8] = {0,0,0,0,0,0,0,0};
            bf16x8 bh = {0,0,0,0,0,0,0,0}, bl = {0,0,0,0,0,0,0,0};
            if (q == 0) {
                const u32* ap = sc + mb * 1000 + 992;
                *(uint4*)(pw)     = *(const uint4*)(ap);
                *(uint4*)(pw + 4) = *(const uint4*)(ap + 4);
                bh = *(const bf16x8*)(bhp + 992);
                bl = *(const bf16x8*)(blp + 992);
            }
            bf16x8 ah, al;
#pragma unroll
            for (int j = 0; j < 8; ++j) {
                ah[j] = (short)(pw[j] & 0xffffu);
                al[j] = (short)(pw[j] >> 16);
            }
            acc = __builtin_amdgcn_mfma_f32_16x16x32_bf16(ah, bh, acc, 0, 0, 0);
            acc = __builtin_amdgcn_mfma_f32_16x16x32_bf16(ah, bl, acc, 0, 0, 0);
            acc = __builtin_amdgcn_mfma_f32_16x16x32_bf16(al, bh, acc, 0, 0, 0);
        }
        __syncthreads();                 // all sc reads done -> overlay
        if (q == 0) {
#pragma unroll
            for (int r = 0; r < 4; ++r)   // D row r = score row r = batch row r
                xb[r * 128 + 64 + wv * 16 + l15] = acc[r] * smf[64 + r];
        }
        {
            int b = t >> 6, e = t & 63;
            xb[b * 128 + e] = ecC[(size_t)(b0 + b) * 64 + e];
        }
    }
    __syncthreads();

    // MLP: wave-local per b = wave id
    {
        const int b = t >> 6, j = t & 63;
        const float* x = xb + b * 128;
        {
            float a = bm1[j];
            const float* wr = Wm1 + j * 128;
#pragma unroll 8
            for (int k = 0; k < 128; ++k) a += x[k] * wr[k];
            xb[512 + b * 64 + j] = fmaxf(a, 0.f);
        }
        __syncthreads();
        if (j < 32) {
            float a = bm2[j];
            const float* wr = Wm2 + j * 64;
#pragma unroll 8
            for (int k = 0; k < 64; ++k) a += xb[512 + b * 64 + k] * wr[k];
            xb[768 + b * 32 + j] = fmaxf(a, 0.f);
        }
        __syncthreads();
        float p = (j < 32) ? xb[768 + b * 32 + j] * Wm3[j] : 0.f;
#pragma unroll
        for (int kk = 1; kk < 64; kk <<= 1) p += __shfl_xor(p, kk);
        if (j == 0) out[b0 + b] = p + bm3[0];
    }
}

extern "C" void kernel_launch(void* const* d_in, const int* in_sizes, int n_in,
                              void* d_out, int out_size, void* d_ws, size_t ws_size,
                              hipStream_t stream) {
    const float* cand  = (const float*)d_in[0];   // (8192,1000) fp32
    const float* rated = (const float*)d_in[1];   // (1000,1000)
    const float* um    = (const float*)d_in[2];   // (8192,1000)
    const float* We    = (const float*)d_in[3];   // (64,1000)
    const float* be    = (const float*)d_in[4];   // (64,)
    const float* Wa1   = (const float*)d_in[5];   // (16,128)
    const float* ba1   = (const float*)d_in[6];   // (16,)
    const float* Wa2   = (const float*)d_in[7];   // (1,16)
    // d_in[8] = ba2: softmax-invariant (exact), skipped
    const float* Wm1   = (const float*)d_in[9];   // (64,128)
    const float* bm1   = (const float*)d_in[10];  // (64,)
    const float* Wm2   = (const float*)d_in[11];  // (32,64)
    const float* bm2   = (const float*)d_in[12];  // (32,)
    const float* Wm3   = (const float*)d_in[13];  // (1,32)
    const float* bm3   = (const float*)d_in[14];  // (1,)

    // ws layout = 2,417,152 B — ceiling proven in-use since round 5.
    float* arw   = (float*)d_ws;                  // 16000 f
    float* ec    = arw + 16000;                   // 524288 f
    u16*   er_th = (u16*)(ec + 524288);           // 64000 u16
    u16*   er_tl = er_th + 64000;                 // 64000 u16
    float* out   = (float*)d_out;

    kemb_rated<<<dim3(63),   dim3(256), 0, stream>>>(rated, We, be, Wa1, er_th, er_tl, arw);
    kemb_mfma <<<dim3(512),  dim3(256), 0, stream>>>(cand, We, be, ec, 8192);
    k3v7      <<<dim3(2048), dim3(256), 0, stream>>>(arw, ec, er_th, er_tl, um,
                                                     Wa1, ba1, Wa2, Wm1, bm1,
                                                     Wm2, bm2, Wm3, bm3, out);
}

// Round 8
// 247.650 us; speedup vs baseline: 1.0594x; 1.0594x over previous
//
#include <hip/hip_runtime.h>

typedef unsigned short u16;
typedef unsigned int   u32;
typedef float f32x4  __attribute__((ext_vector_type(4)));
typedef short bf16x8 __attribute__((ext_vector_type(8)));

__device__ __forceinline__ u16 f2b_rne(float x) {
    u32 u = __float_as_uint(x);
    return (u16)((u + 0x7fffu + ((u >> 16) & 1u)) >> 16);
}
__device__ __forceinline__ float b2f(u16 u) { return __uint_as_float((u32)u << 16); }
__device__ __forceinline__ void split1(float x, u16& h, u16& l) {
    h = f2b_rne(x);
    l = f2b_rne(x - b2f(h));
}
__device__ __forceinline__ void mk_frag(f32x4 a, f32x4 b, bf16x8& hi, bf16x8& lo) {
#pragma unroll
    for (int j = 0; j < 4; ++j) { u16 h, l; split1(a[j], h, l); hi[j] = (short)h; lo[j] = (short)l; }
#pragma unroll
    for (int j = 0; j < 4; ++j) { u16 h, l; split1(b[j], h, l); hi[4+j] = (short)h; lo[4+j] = (short)l; }
}

// ---------------------------------------------------------------------------
// kemb_mfma (cand): ec[M x 64](fp32) = X @ We^T + be, split-bf16 MFMA.
// Verbatim from rounds 5-7 (proven PASS @ absmax 2e-3).
// ---------------------------------------------------------------------------
__global__ __launch_bounds__(256) void kemb_mfma(
    const float* __restrict__ X, const float* __restrict__ W, const float* __restrict__ be,
    float* __restrict__ out, int M)
{
    const int wv   = threadIdx.x >> 6;
    const int lane = threadIdx.x & 63;
    const int l15  = lane & 15;
    const int q    = lane >> 4;

    const int arow = min(blockIdx.x * 16 + l15, M - 1);
    const float* xr = X + (size_t)arow * 1000;
    const float* wr = W + (size_t)(wv * 16 + l15) * 1000;

    const float bias = be[wv * 16 + l15];
    f32x4 acc = {bias, bias, bias, bias};

    for (int kc = 0; kc < 992; kc += 32) {
        bf16x8 ah, al, bh, bl;
        mk_frag(*(const f32x4*)(xr + kc + q * 8), *(const f32x4*)(xr + kc + q * 8 + 4), ah, al);
        mk_frag(*(const f32x4*)(wr + kc + q * 8), *(const f32x4*)(wr + kc + q * 8 + 4), bh, bl);
        acc = __builtin_amdgcn_mfma_f32_16x16x32_bf16(ah, bh, acc, 0, 0, 0);
        acc = __builtin_amdgcn_mfma_f32_16x16x32_bf16(ah, bl, acc, 0, 0, 0);
        acc = __builtin_amdgcn_mfma_f32_16x16x32_bf16(al, bh, acc, 0, 0, 0);
    }
    {
        bf16x8 ah = {0,0,0,0,0,0,0,0}, al = {0,0,0,0,0,0,0,0};
        bf16x8 bh = {0,0,0,0,0,0,0,0}, bl = {0,0,0,0,0,0,0,0};
        if (q == 0) {
            mk_frag(*(const f32x4*)(xr + 992), *(const f32x4*)(xr + 996), ah, al);
            mk_frag(*(const f32x4*)(wr + 992), *(const f32x4*)(wr + 996), bh, bl);
        }
        acc = __builtin_amdgcn_mfma_f32_16x16x32_bf16(ah, bh, acc, 0, 0, 0);
        acc = __builtin_amdgcn_mfma_f32_16x16x32_bf16(ah, bl, acc, 0, 0, 0);
        acc = __builtin_amdgcn_mfma_f32_16x16x32_bf16(al, bh, acc, 0, 0, 0);
    }
#pragma unroll
    for (int r = 0; r < 4; ++r) {
        int m = blockIdx.x * 16 + q * 4 + r;
        if (m < M) out[(size_t)m * 64 + wv * 16 + l15] = acc[r];
    }
}

// ---------------------------------------------------------------------------
// kemb_rated: GEMM for rated (M=1000); emits er_t (transposed split-bf16)
// and ar via in-kernel MFMA. Verbatim from rounds 6/7 (proven).
// ---------------------------------------------------------------------------
__global__ __launch_bounds__(256) void kemb_rated(
    const float* __restrict__ X, const float* __restrict__ W, const float* __restrict__ be,
    const float* __restrict__ Wa1,
    u16* __restrict__ er_th, u16* __restrict__ er_tl, float* __restrict__ ar)
{
    __shared__ float smt[16 * 68];
    const int wv   = threadIdx.x >> 6;
    const int lane = threadIdx.x & 63;
    const int l15  = lane & 15;
    const int q    = lane >> 4;
    const int i0   = blockIdx.x * 16;

    const int arow = min(i0 + l15, 999);
    const float* xr = X + (size_t)arow * 1000;
    const float* wr = W + (size_t)(wv * 16 + l15) * 1000;

    const float bias = be[wv * 16 + l15];
    f32x4 acc = {bias, bias, bias, bias};

    for (int kc = 0; kc < 992; kc += 32) {
        bf16x8 ah, al, bh, bl;
        mk_frag(*(const f32x4*)(xr + kc + q * 8), *(const f32x4*)(xr + kc + q * 8 + 4), ah, al);
        mk_frag(*(const f32x4*)(wr + kc + q * 8), *(const f32x4*)(wr + kc + q * 8 + 4), bh, bl);
        acc = __builtin_amdgcn_mfma_f32_16x16x32_bf16(ah, bh, acc, 0, 0, 0);
        acc = __builtin_amdgcn_mfma_f32_16x16x32_bf16(ah, bl, acc, 0, 0, 0);
        acc = __builtin_amdgcn_mfma_f32_16x16x32_bf16(al, bh, acc, 0, 0, 0);
    }
    {
        bf16x8 ah = {0,0,0,0,0,0,0,0}, al = {0,0,0,0,0,0,0,0};
        bf16x8 bh = {0,0,0,0,0,0,0,0}, bl = {0,0,0,0,0,0,0,0};
        if (q == 0) {
            mk_frag(*(const f32x4*)(xr + 992), *(const f32x4*)(xr + 996), ah, al);
            mk_frag(*(const f32x4*)(wr + 992), *(const f32x4*)(wr + 996), bh, bl);
        }
        acc = __builtin_amdgcn_mfma_f32_16x16x32_bf16(ah, bh, acc, 0, 0, 0);
        acc = __builtin_amdgcn_mfma_f32_16x16x32_bf16(ah, bl, acc, 0, 0, 0);
        acc = __builtin_amdgcn_mfma_f32_16x16x32_bf16(al, bh, acc, 0, 0, 0);
    }

    const int e = wv * 16 + l15;
#pragma unroll
    for (int r = 0; r < 4; ++r) {
        int i = i0 + q * 4 + r;
        smt[(q * 4 + r) * 68 + e] = acc[r];
        if (i < 1000) {
            u16 h, l; split1(acc[r], h, l);
            er_th[(size_t)e * 1000 + i] = h;
            er_tl[(size_t)e * 1000 + i] = l;
        }
    }
    __syncthreads();

    if (wv == 0) {
        f32x4 a2 = {0.f, 0.f, 0.f, 0.f};
#pragma unroll
        for (int kc = 0; kc < 64; kc += 32) {
            const float* ap = smt + l15 * 68 + kc + q * 8;
            const float* bp = Wa1 + l15 * 128 + 64 + kc + q * 8;
            bf16x8 ah, al, bh, bl;
            mk_frag(*(const f32x4*)ap, *(const f32x4*)(ap + 4), ah, al);
            mk_frag(*(const f32x4*)bp, *(const f32x4*)(bp + 4), bh, bl);
            a2 = __builtin_amdgcn_mfma_f32_16x16x32_bf16(ah, bh, a2, 0, 0, 0);
            a2 = __builtin_amdgcn_mfma_f32_16x16x32_bf16(ah, bl, a2, 0, 0, 0);
            a2 = __builtin_amdgcn_mfma_f32_16x16x32_bf16(al, bh, a2, 0, 0, 0);
        }
#pragma unroll
        for (int r = 0; r < 4; ++r) {
            int i = i0 + q * 4 + r;
            if (i < 1000) ar[(size_t)i * 16 + l15] = a2[r];
        }
    }
}

// ---------------------------------------------------------------------------
// k3v8: round-6 structure (8 batch rows, LDS 34.8 KB, pitch-1004 sc) but
// 512 THREADS (8 waves) per block. Occupancy hypothesis: the residency cap
// is ~4 workgroups/CU (LDS-independent, falsified LDS theory in round 7);
// 8-wave blocks then give 32 waves/CU instead of 16.
// LDS: sc[8][1004] u32; smf: EC[8][65] @0, ACL[8][16] @520, SUMS[8] @648.
// Overlay (after P2 reads): XB[8][128] @0, PA[2][8][64] @2048, H1 @1024,
// H2 @1536 (floats, all < 8032).
// P2 splits K across wave pairs (h = wv>>2): total MFMA = round-6 level.
// ---------------------------------------------------------------------------
__global__ __launch_bounds__(512, 8) void k3v8(
    const float* __restrict__ ar, const float* __restrict__ ecC,
    const u16* __restrict__ er_th, const u16* __restrict__ er_tl,
    const float* __restrict__ um, const float* __restrict__ Wa1, const float* __restrict__ ba1,
    const float* __restrict__ Wa2,
    const float* __restrict__ Wm1, const float* __restrict__ bm1,
    const float* __restrict__ Wm2, const float* __restrict__ bm2,
    const float* __restrict__ Wm3, const float* __restrict__ bm3,
    float* __restrict__ out)
{
    __shared__ u32   sc[8 * 1004];
    __shared__ float smf[656];
    float* xb = (float*)sc;
    const int t  = threadIdx.x;
    const int b0 = blockIdx.x * 8;

    // EC load: one element per thread
    {
        const int b = t >> 6, e = t & 63;
        smf[b * 65 + e] = ecC[(size_t)(b0 + b) * 64 + e];
    }
    __syncthreads();

    // ACL[b][a] = ba1[a] + EC[b] . W1c[a]
    if (t < 128) {
        const int b = t & 7, a = t >> 3;
        float acc = ba1[a];
        const float* w = Wa1 + a * 128;
#pragma unroll 8
        for (int e = 0; e < 64; ++e) acc += smf[b * 65 + e] * w[e];
        smf[520 + b * 16 + a] = acc;
    }
    __syncthreads();

    // P1: sc[b][i] = sum_a relu(ACL[b][a] + ar[i][a]) * Wa2[a]
    {
        const int b = t & 7, c = t >> 3;          // c in [0,64)
        float acb[16], w2[16];
#pragma unroll
        for (int a = 0; a < 16; ++a) acb[a] = smf[520 + b * 16 + a];
#pragma unroll
        for (int a = 0; a < 16; ++a) w2[a] = Wa2[a];
#pragma unroll 3
        for (int j = 0; j < 15; ++j) {            // i = c + 64j <= 959, always valid
            int i = c + 64 * j;
            const f32x4* a4 = (const f32x4*)(ar + (size_t)i * 16);
            f32x4 r0 = a4[0], r1 = a4[1], r2 = a4[2], r3 = a4[3];
            float s = 0.f;
            s += fmaxf(acb[0]  + r0[0], 0.f) * w2[0];
            s += fmaxf(acb[1]  + r0[1], 0.f) * w2[1];
            s += fmaxf(acb[2]  + r0[2], 0.f) * w2[2];
            s += fmaxf(acb[3]  + r0[3], 0.f) * w2[3];
            s += fmaxf(acb[4]  + r1[0], 0.f) * w2[4];
            s += fmaxf(acb[5]  + r1[1], 0.f) * w2[5];
            s += fmaxf(acb[6]  + r1[2], 0.f) * w2[6];
            s += fmaxf(acb[7]  + r1[3], 0.f) * w2[7];
            s += fmaxf(acb[8]  + r2[0], 0.f) * w2[8];
            s += fmaxf(acb[9]  + r2[1], 0.f) * w2[9];
            s += fmaxf(acb[10] + r2[2], 0.f) * w2[10];
            s += fmaxf(acb[11] + r2[3], 0.f) * w2[11];
            s += fmaxf(acb[12] + r3[0], 0.f) * w2[12];
            s += fmaxf(acb[13] + r3[1], 0.f) * w2[13];
            s += fmaxf(acb[14] + r3[2], 0.f) * w2[14];
            s += fmaxf(acb[15] + r3[3], 0.f) * w2[15];
            sc[b * 1004 + i] = __float_as_uint(s);
        }
        {   // j = 15: i = 960 + c, valid iff c < 40
            int i = 960 + c;
            if (i < 1000) {
                const f32x4* a4 = (const f32x4*)(ar + (size_t)i * 16);
                f32x4 r0 = a4[0], r1 = a4[1], r2 = a4[2], r3 = a4[3];
                float s = 0.f;
#pragma unroll
                for (int v = 0; v < 4; ++v) {
                    f32x4 rv = (v == 0) ? r0 : (v == 1) ? r1 : (v == 2) ? r2 : r3;
                    s += fmaxf(acb[4*v+0] + rv[0], 0.f) * w2[4*v+0];
                    s += fmaxf(acb[4*v+1] + rv[1], 0.f) * w2[4*v+1];
                    s += fmaxf(acb[4*v+2] + rv[2], 0.f) * w2[4*v+2];
                    s += fmaxf(acb[4*v+3] + rv[3], 0.f) * w2[4*v+3];
                }
                sc[b * 1004 + i] = __float_as_uint(s);
            }
        }
    }
    __syncthreads();

    // softmax (wave-local: b = wave id 0..7); pack P = exp(s-m)*um split-bf16
    {
        const int b = t >> 6, g = t & 63;
        float m = -1e30f;
        for (int i = g; i < 1000; i += 64) m = fmaxf(m, __uint_as_float(sc[b * 1004 + i]));
#pragma unroll
        for (int k = 1; k < 64; k <<= 1) m = fmaxf(m, __shfl_xor(m, k));
        float sum = 0.f;
        const float* umr = um + (size_t)(b0 + b) * 1000;
        for (int i = g; i < 1000; i += 64) {
            float w = __expf(__uint_as_float(sc[b * 1004 + i]) - m);
            sum += w;
            float p = w * umr[i];
            u16 h, l; split1(p, h, l);
            sc[b * 1004 + i] = (u32)h | ((u32)l << 16);
        }
#pragma unroll
        for (int k = 1; k < 64; k <<= 1) sum += __shfl_xor(sum, k);
        if (g == 0) smf[648 + b] = 1.0f / sum;
    }
    __syncthreads();

    // P2: user_emb via MFMA. wave wv: e-tile = wv&3, K-half = wv>>2.
    {
        const int wv = t >> 6, lane = t & 63, l15 = lane & 15, q = lane >> 4;
        const int et = wv & 3, h = wv >> 2;
        const int m8 = l15 & 7;
        const u16* bhp = er_th + (size_t)(et * 16 + l15) * 1000;
        const u16* blp = er_tl + (size_t)(et * 16 + l15) * 1000;
        f32x4 acc = {0.f, 0.f, 0.f, 0.f};

        const int kc0 = h ? 512 : 0;
        const int kc1 = h ? 992 : 512;
        for (int kc = kc0; kc < kc1; kc += 32) {
            const u32* ap = sc + m8 * 1004 + kc + q * 8;
            u32 pw[8];
            *(uint4*)(pw)     = *(const uint4*)(ap);
            *(uint4*)(pw + 4) = *(const uint4*)(ap + 4);
            bf16x8 ah, al;
#pragma unroll
            for (int j = 0; j < 8; ++j) {
                ah[j] = (short)(pw[j] & 0xffffu);
                al[j] = (short)(pw[j] >> 16);
            }
            bf16x8 bh = *(const bf16x8*)(bhp + kc + q * 8);
            bf16x8 bl = *(const bf16x8*)(blp + kc + q * 8);
            acc = __builtin_amdgcn_mfma_f32_16x16x32_bf16(ah, bh, acc, 0, 0, 0);
            acc = __builtin_amdgcn_mfma_f32_16x16x32_bf16(ah, bl, acc, 0, 0, 0);
            acc = __builtin_amdgcn_mfma_f32_16x16x32_bf16(al, bh, acc, 0, 0, 0);
        }
        if (h == 1) {   // K tail 992..999 (q==0 lanes only hold live data)
            u32 pw[8] = {0,0,0,0,0,0,0,0};
            bf16x8 bh = {0,0,0,0,0,0,0,0}, bl = {0,0,0,0,0,0,0,0};
            if (q == 0) {
                const u32* ap = sc + m8 * 1004 + 992;
                *(uint4*)(pw)     = *(const uint4*)(ap);
                *(uint4*)(pw + 4) = *(const uint4*)(ap + 4);
                bh = *(const bf16x8*)(bhp + 992);
                bl = *(const bf16x8*)(blp + 992);
            }
            bf16x8 ah, al;
#pragma unroll
            for (int j = 0; j < 8; ++j) {
                ah[j] = (short)(pw[j] & 0xffffu);
                al[j] = (short)(pw[j] >> 16);
            }
            acc = __builtin_amdgcn_mfma_f32_16x16x32_bf16(ah, bh, acc, 0, 0, 0);
            acc = __builtin_amdgcn_mfma_f32_16x16x32_bf16(ah, bl, acc, 0, 0, 0);
            acc = __builtin_amdgcn_mfma_f32_16x16x32_bf16(al, bh, acc, 0, 0, 0);
        }
        __syncthreads();                  // all sc reads complete -> overlay legal
        if (q < 2) {                      // D rows 0..7 = batch rows (rows 8..15 dup)
#pragma unroll
            for (int r = 0; r < 4; ++r) {
                int b = q * 4 + r;
                xb[2048 + h * 512 + b * 64 + et * 16 + l15] = acc[r];
            }
        }
    }
    __syncthreads();

    // P2b: sum the two K-half partials, scale, build x = [EC | user_emb]
    {
        const int b = t >> 6, e = t & 63;
        float v = (xb[2048 + b * 64 + e] + xb[2560 + b * 64 + e]) * smf[648 + b];
        float ecv = smf[b * 65 + e];
        xb[b * 128 + 64 + e] = v;
        xb[b * 128 + e] = ecv;
    }
    __syncthreads();

    // MLP: wave-local per b = wave id (8 waves = 8 rows), j = lane
    {
        const int b = t >> 6, j = t & 63;
        const float* x = xb + b * 128;
        {
            float a = bm1[j];
            const float* wr = Wm1 + j * 128;
#pragma unroll 8
            for (int k = 0; k < 128; ++k) a += x[k] * wr[k];
            xb[1024 + b * 64 + j] = fmaxf(a, 0.f);
        }
        __syncthreads();
        if (j < 32) {
            float a = bm2[j];
            const float* wr = Wm2 + j * 64;
#pragma unroll 8
            for (int k = 0; k < 64; ++k) a += xb[1024 + b * 64 + k] * wr[k];
            xb[1536 + b * 32 + j] = fmaxf(a, 0.f);
        }
        __syncthreads();
        float p = (j < 32) ? xb[1536 + b * 32 + j] * Wm3[j] : 0.f;
#pragma unroll
        for (int kk = 1; kk < 64; kk <<= 1) p += __shfl_xor(p, kk);
        if (j == 0) out[b0 + b] = p + bm3[0];
    }
}

extern "C" void kernel_launch(void* const* d_in, const int* in_sizes, int n_in,
                              void* d_out, int out_size, void* d_ws, size_t ws_size,
                              hipStream_t stream) {
    const float* cand  = (const float*)d_in[0];   // (8192,1000) fp32
    const float* rated = (const float*)d_in[1];   // (1000,1000)
    const float* um    = (const float*)d_in[2];   // (8192,1000)
    const float* We    = (const float*)d_in[3];   // (64,1000)
    const float* be    = (const float*)d_in[4];   // (64,)
    const float* Wa1   = (const float*)d_in[5];   // (16,128)
    const float* ba1   = (const float*)d_in[6];   // (16,)
    const float* Wa2   = (const float*)d_in[7];   // (1,16)
    // d_in[8] = ba2: softmax-invariant (exact), skipped
    const float* Wm1   = (const float*)d_in[9];   // (64,128)
    const float* bm1   = (const float*)d_in[10];  // (64,)
    const float* Wm2   = (const float*)d_in[11];  // (32,64)
    const float* bm2   = (const float*)d_in[12];  // (32,)
    const float* Wm3   = (const float*)d_in[13];  // (1,32)
    const float* bm3   = (const float*)d_in[14];  // (1,)

    // ws layout = 2,417,152 B — ceiling proven in-use since round 5.
    float* arw   = (float*)d_ws;                  // 16000 f
    float* ec    = arw + 16000;                   // 524288 f
    u16*   er_th = (u16*)(ec + 524288);           // 64000 u16
    u16*   er_tl = er_th + 64000;                 // 64000 u16
    float* out   = (float*)d_out;

    kemb_rated<<<dim3(63),   dim3(256), 0, stream>>>(rated, We, be, Wa1, er_th, er_tl, arw);
    kemb_mfma <<<dim3(512),  dim3(256), 0, stream>>>(cand, We, be, ec, 8192);
    k3v8      <<<dim3(1024), dim3(512), 0, stream>>>(arw, ec, er_th, er_tl, um,
                                                     Wa1, ba1, Wa2, Wm1, bm1,
                                                     Wm2, bm2, Wm3, bm3, out);
}

// Round 9
// 240.700 us; speedup vs baseline: 1.0900x; 1.0289x over previous
//
#include <hip/hip_runtime.h>

typedef unsigned short u16;
typedef unsigned int   u32;
typedef float f32x4  __attribute__((ext_vector_type(4)));
typedef short bf16x8 __attribute__((ext_vector_type(8)));

__device__ __forceinline__ u16 f2b_rne(float x) {
    u32 u = __float_as_uint(x);
    return (u16)((u + 0x7fffu + ((u >> 16) & 1u)) >> 16);
}
__device__ __forceinline__ float b2f(u16 u) { return __uint_as_float((u32)u << 16); }
__device__ __forceinline__ void split1(float x, u16& h, u16& l) {
    h = f2b_rne(x);
    l = f2b_rne(x - b2f(h));
}
__device__ __forceinline__ void mk_frag(f32x4 a, f32x4 b, bf16x8& hi, bf16x8& lo) {
#pragma unroll
    for (int j = 0; j < 4; ++j) { u16 h, l; split1(a[j], h, l); hi[j] = (short)h; lo[j] = (short)l; }
#pragma unroll
    for (int j = 0; j < 4; ++j) { u16 h, l; split1(b[j], h, l); hi[4+j] = (short)h; lo[4+j] = (short)l; }
}

// ---------------------------------------------------------------------------
// kemb_mfma (cand): ec[M x 64](fp32) = X @ We^T + be, split-bf16 MFMA.
// Verbatim from rounds 5-8 (proven PASS @ absmax 2e-3).
// ---------------------------------------------------------------------------
__global__ __launch_bounds__(256) void kemb_mfma(
    const float* __restrict__ X, const float* __restrict__ W, const float* __restrict__ be,
    float* __restrict__ out, int M)
{
    const int wv   = threadIdx.x >> 6;
    const int lane = threadIdx.x & 63;
    const int l15  = lane & 15;
    const int q    = lane >> 4;

    const int arow = min(blockIdx.x * 16 + l15, M - 1);
    const float* xr = X + (size_t)arow * 1000;
    const float* wr = W + (size_t)(wv * 16 + l15) * 1000;

    const float bias = be[wv * 16 + l15];
    f32x4 acc = {bias, bias, bias, bias};

    for (int kc = 0; kc < 992; kc += 32) {
        bf16x8 ah, al, bh, bl;
        mk_frag(*(const f32x4*)(xr + kc + q * 8), *(const f32x4*)(xr + kc + q * 8 + 4), ah, al);
        mk_frag(*(const f32x4*)(wr + kc + q * 8), *(const f32x4*)(wr + kc + q * 8 + 4), bh, bl);
        acc = __builtin_amdgcn_mfma_f32_16x16x32_bf16(ah, bh, acc, 0, 0, 0);
        acc = __builtin_amdgcn_mfma_f32_16x16x32_bf16(ah, bl, acc, 0, 0, 0);
        acc = __builtin_amdgcn_mfma_f32_16x16x32_bf16(al, bh, acc, 0, 0, 0);
    }
    {
        bf16x8 ah = {0,0,0,0,0,0,0,0}, al = {0,0,0,0,0,0,0,0};
        bf16x8 bh = {0,0,0,0,0,0,0,0}, bl = {0,0,0,0,0,0,0,0};
        if (q == 0) {
            mk_frag(*(const f32x4*)(xr + 992), *(const f32x4*)(xr + 996), ah, al);
            mk_frag(*(const f32x4*)(wr + 992), *(const f32x4*)(wr + 996), bh, bl);
        }
        acc = __builtin_amdgcn_mfma_f32_16x16x32_bf16(ah, bh, acc, 0, 0, 0);
        acc = __builtin_amdgcn_mfma_f32_16x16x32_bf16(ah, bl, acc, 0, 0, 0);
        acc = __builtin_amdgcn_mfma_f32_16x16x32_bf16(al, bh, acc, 0, 0, 0);
    }
#pragma unroll
    for (int r = 0; r < 4; ++r) {
        int m = blockIdx.x * 16 + q * 4 + r;
        if (m < M) out[(size_t)m * 64 + wv * 16 + l15] = acc[r];
    }
}

// ---------------------------------------------------------------------------
// kemb_rated: GEMM for rated (M=1000); emits er_t (transposed split-bf16)
// and ar via in-kernel MFMA. Verbatim from rounds 6-8 (proven).
// ---------------------------------------------------------------------------
__global__ __launch_bounds__(256) void kemb_rated(
    const float* __restrict__ X, const float* __restrict__ W, const float* __restrict__ be,
    const float* __restrict__ Wa1,
    u16* __restrict__ er_th, u16* __restrict__ er_tl, float* __restrict__ ar)
{
    __shared__ float smt[16 * 68];
    const int wv   = threadIdx.x >> 6;
    const int lane = threadIdx.x & 63;
    const int l15  = lane & 15;
    const int q    = lane >> 4;
    const int i0   = blockIdx.x * 16;

    const int arow = min(i0 + l15, 999);
    const float* xr = X + (size_t)arow * 1000;
    const float* wr = W + (size_t)(wv * 16 + l15) * 1000;

    const float bias = be[wv * 16 + l15];
    f32x4 acc = {bias, bias, bias, bias};

    for (int kc = 0; kc < 992; kc += 32) {
        bf16x8 ah, al, bh, bl;
        mk_frag(*(const f32x4*)(xr + kc + q * 8), *(const f32x4*)(xr + kc + q * 8 + 4), ah, al);
        mk_frag(*(const f32x4*)(wr + kc + q * 8), *(const f32x4*)(wr + kc + q * 8 + 4), bh, bl);
        acc = __builtin_amdgcn_mfma_f32_16x16x32_bf16(ah, bh, acc, 0, 0, 0);
        acc = __builtin_amdgcn_mfma_f32_16x16x32_bf16(ah, bl, acc, 0, 0, 0);
        acc = __builtin_amdgcn_mfma_f32_16x16x32_bf16(al, bh, acc, 0, 0, 0);
    }
    {
        bf16x8 ah = {0,0,0,0,0,0,0,0}, al = {0,0,0,0,0,0,0,0};
        bf16x8 bh = {0,0,0,0,0,0,0,0}, bl = {0,0,0,0,0,0,0,0};
        if (q == 0) {
            mk_frag(*(const f32x4*)(xr + 992), *(const f32x4*)(xr + 996), ah, al);
            mk_frag(*(const f32x4*)(wr + 992), *(const f32x4*)(wr + 996), bh, bl);
        }
        acc = __builtin_amdgcn_mfma_f32_16x16x32_bf16(ah, bh, acc, 0, 0, 0);
        acc = __builtin_amdgcn_mfma_f32_16x16x32_bf16(ah, bl, acc, 0, 0, 0);
        acc = __builtin_amdgcn_mfma_f32_16x16x32_bf16(al, bh, acc, 0, 0, 0);
    }

    const int e = wv * 16 + l15;
#pragma unroll
    for (int r = 0; r < 4; ++r) {
        int i = i0 + q * 4 + r;
        smt[(q * 4 + r) * 68 + e] = acc[r];
        if (i < 1000) {
            u16 h, l; split1(acc[r], h, l);
            er_th[(size_t)e * 1000 + i] = h;
            er_tl[(size_t)e * 1000 + i] = l;
        }
    }
    __syncthreads();

    if (wv == 0) {
        f32x4 a2 = {0.f, 0.f, 0.f, 0.f};
#pragma unroll
        for (int kc = 0; kc < 64; kc += 32) {
            const float* ap = smt + l15 * 68 + kc + q * 8;
            const float* bp = Wa1 + l15 * 128 + 64 + kc + q * 8;
            bf16x8 ah, al, bh, bl;
            mk_frag(*(const f32x4*)ap, *(const f32x4*)(ap + 4), ah, al);
            mk_frag(*(const f32x4*)bp, *(const f32x4*)(bp + 4), bh, bl);
            a2 = __builtin_amdgcn_mfma_f32_16x16x32_bf16(ah, bh, a2, 0, 0, 0);
            a2 = __builtin_amdgcn_mfma_f32_16x16x32_bf16(ah, bl, a2, 0, 0, 0);
            a2 = __builtin_amdgcn_mfma_f32_16x16x32_bf16(al, bh, a2, 0, 0, 0);
        }
#pragma unroll
        for (int r = 0; r < 4; ++r) {
            int i = i0 + q * 4 + r;
            if (i < 1000) ar[(size_t)i * 16 + l15] = a2[r];
        }
    }
}

// ---------------------------------------------------------------------------
// k3v9: 8 rows/block, 512 threads. Fixes vs v8 (86 us, 30% VALU, stall-bound):
//  - P1: thread-per-i computing ALL 8 b's -> ar rows read once per block
//    (8x fewer L2 loads), coalesced, 8 independent FMA chains (ILP).
//  - softmax: score row -> REGISTERS, barrier, then write P as two separate
//    u16 bf16 planes ph/pl (pitch 1008, 16B-aligned rows) over the dead
//    score region. P2 A-frags become direct ds_read_b128 — zero unpack VALU.
// LDS: S = 8x1008 u32 (32256 B; f32 scores, then ph @0 / pl @8064 u16,
// then f32 overlay: PA[2][8][64] @0, XB[8][128] @1024, H1 @2048, H2 @2560),
// ACL[128], SUMS[8]. Total ~32.8 KB -> 4 blocks/CU, 32 waves/CU.
// ---------------------------------------------------------------------------
__global__ __launch_bounds__(512, 8) void k3v9(
    const float* __restrict__ ar, const float* __restrict__ ecC,
    const u16* __restrict__ er_th, const u16* __restrict__ er_tl,
    const float* __restrict__ um, const float* __restrict__ Wa1, const float* __restrict__ ba1,
    const float* __restrict__ Wa2,
    const float* __restrict__ Wm1, const float* __restrict__ bm1,
    const float* __restrict__ Wm2, const float* __restrict__ bm2,
    const float* __restrict__ Wm3, const float* __restrict__ bm3,
    float* __restrict__ out)
{
    __shared__ u32   S[8 * 1008];
    __shared__ float ACL[128];
    __shared__ float SUMS[8];
    u16*   S16 = (u16*)S;
    float* Sf  = (float*)S;
    const int t  = threadIdx.x;
    const int b0 = blockIdx.x * 8;

    // A: ACL[b][a] = ba1[a] + ec[b0+b] . W1c[a]
    if (t < 128) {
        const int b = t & 7, a = t >> 3;
        float acc = ba1[a];
        const float* ecr = ecC + (size_t)(b0 + b) * 64;
        const float* w = Wa1 + a * 128;
#pragma unroll 8
        for (int e = 0; e < 64; ++e) acc += ecr[e] * w[e];
        ACL[b * 16 + a] = acc;
    }
    __syncthreads();                                        // B1

    // P1: thread t -> items i = t, t+512; computes scores for all 8 b's.
    {
        float w2[16];
#pragma unroll
        for (int a = 0; a < 16; ++a) w2[a] = Wa2[a];
#pragma unroll
        for (int rep = 0; rep < 2; ++rep) {
            const int i = t + rep * 512;
            if (i < 1000) {
                const f32x4* a4 = (const f32x4*)(ar + (size_t)i * 16);
                f32x4 r0 = a4[0], r1 = a4[1], r2 = a4[2], r3 = a4[3];
#pragma unroll
                for (int b = 0; b < 8; ++b) {
                    const f32x4* ac4 = (const f32x4*)(ACL + b * 16);
                    f32x4 c0 = ac4[0], c1 = ac4[1], c2 = ac4[2], c3 = ac4[3];
                    float s0 = 0.f, s1 = 0.f;                // split chains
                    s0 += fmaxf(c0[0] + r0[0], 0.f) * w2[0];
                    s1 += fmaxf(c0[1] + r0[1], 0.f) * w2[1];
                    s0 += fmaxf(c0[2] + r0[2], 0.f) * w2[2];
                    s1 += fmaxf(c0[3] + r0[3], 0.f) * w2[3];
                    s0 += fmaxf(c1[0] + r1[0], 0.f) * w2[4];
                    s1 += fmaxf(c1[1] + r1[1], 0.f) * w2[5];
                    s0 += fmaxf(c1[2] + r1[2], 0.f) * w2[6];
                    s1 += fmaxf(c1[3] + r1[3], 0.f) * w2[7];
                    s0 += fmaxf(c2[0] + r2[0], 0.f) * w2[8];
                    s1 += fmaxf(c2[1] + r2[1], 0.f) * w2[9];
                    s0 += fmaxf(c2[2] + r2[2], 0.f) * w2[10];
                    s1 += fmaxf(c2[3] + r2[3], 0.f) * w2[11];
                    s0 += fmaxf(c3[0] + r3[0], 0.f) * w2[12];
                    s1 += fmaxf(c3[1] + r3[1], 0.f) * w2[13];
                    s0 += fmaxf(c3[2] + r3[2], 0.f) * w2[14];
                    s1 += fmaxf(c3[3] + r3[3], 0.f) * w2[15];
                    Sf[b * 1008 + i] = s0 + s1;
                }
            }
        }
    }
    __syncthreads();                                        // B2

    // softmax (wave-local, b = wave id): scores -> regs, barrier, write ph/pl
    {
        const int b = t >> 6, g = t & 63;
        float sv[16], uv[16];
#pragma unroll
        for (int k = 0; k < 16; ++k) {
            int i = g + 64 * k;
            sv[k] = (i < 1000) ? Sf[b * 1008 + i] : -1e30f;
        }
        float m = -1e30f;
#pragma unroll
        for (int k = 0; k < 16; ++k) m = fmaxf(m, sv[k]);
#pragma unroll
        for (int k = 1; k < 64; k <<= 1) m = fmaxf(m, __shfl_xor(m, k));
        const float* umr = um + (size_t)(b0 + b) * 1000;
#pragma unroll
        for (int k = 0; k < 16; ++k) {
            int i = g + 64 * k;
            uv[k] = (i < 1000) ? umr[i] : 0.f;
        }
        __syncthreads();                                    // B3: scores in regs
        float sum = 0.f;
#pragma unroll
        for (int k = 0; k < 16; ++k) {
            int i = g + 64 * k;
            if (i < 1000) {
                float w = __expf(sv[k] - m);
                sum += w;
                float p = w * uv[k];
                u16 h, l; split1(p, h, l);
                S16[b * 1008 + i] = h;            // ph plane
                S16[8064 + b * 1008 + i] = l;     // pl plane
            }
        }
#pragma unroll
        for (int k = 1; k < 64; k <<= 1) sum += __shfl_xor(sum, k);
        if (g == 0) SUMS[b] = 1.0f / sum;
    }
    __syncthreads();                                        // B4

    // P2: user_emb via MFMA. wave wv: e-tile = wv&3, K-half = wv>>2.
    {
        const int wv = t >> 6, lane = t & 63, l15 = lane & 15, q = lane >> 4;
        const int et = wv & 3, h = wv >> 2;
        const int m8 = l15 & 7;
        const u16* php = S16 + m8 * 1008;
        const u16* plp = S16 + 8064 + m8 * 1008;
        const u16* bhp = er_th + (size_t)(et * 16 + l15) * 1000;
        const u16* blp = er_tl + (size_t)(et * 16 + l15) * 1000;
        f32x4 acc = {0.f, 0.f, 0.f, 0.f};

        const int kc0 = h ? 512 : 0;
        const int kc1 = h ? 992 : 512;
        for (int kc = kc0; kc < kc1; kc += 32) {
            bf16x8 ah = *(const bf16x8*)(php + kc + q * 8);   // direct, no unpack
            bf16x8 al = *(const bf16x8*)(plp + kc + q * 8);
            bf16x8 bh = *(const bf16x8*)(bhp + kc + q * 8);
            bf16x8 bl = *(const bf16x8*)(blp + kc + q * 8);
            acc = __builtin_amdgcn_mfma_f32_16x16x32_bf16(ah, bh, acc, 0, 0, 0);
            acc = __builtin_amdgcn_mfma_f32_16x16x32_bf16(ah, bl, acc, 0, 0, 0);
            acc = __builtin_amdgcn_mfma_f32_16x16x32_bf16(al, bh, acc, 0, 0, 0);
        }
        if (h == 1) {   // K tail 992..999 (q==0 lanes hold live data)
            bf16x8 ah = {0,0,0,0,0,0,0,0}, al = {0,0,0,0,0,0,0,0};
            bf16x8 bh = {0,0,0,0,0,0,0,0}, bl = {0,0,0,0,0,0,0,0};
            if (q == 0) {
                ah = *(const bf16x8*)(php + 992);
                al = *(const bf16x8*)(plp + 992);
                bh = *(const bf16x8*)(bhp + 992);
                bl = *(const bf16x8*)(blp + 992);
            }
            acc = __builtin_amdgcn_mfma_f32_16x16x32_bf16(ah, bh, acc, 0, 0, 0);
            acc = __builtin_amdgcn_mfma_f32_16x16x32_bf16(ah, bl, acc, 0, 0, 0);
            acc = __builtin_amdgcn_mfma_f32_16x16x32_bf16(al, bh, acc, 0, 0, 0);
        }
        __syncthreads();                                    // B5: P reads done
        if (q < 2) {                      // D rows 0..7 = batch rows (8..15 dup)
#pragma unroll
            for (int r = 0; r < 4; ++r) {
                int b = q * 4 + r;
                Sf[h * 512 + b * 64 + et * 16 + l15] = acc[r];   // PA overlay
            }
        }
    }
    __syncthreads();                                        // B6

    // P2b: combine K-halves, scale, build x = [ec | user_emb]
    {
        const int b = t >> 6, e = t & 63;
        float v = (Sf[b * 64 + e] + Sf[512 + b * 64 + e]) * SUMS[b];
        Sf[1024 + b * 128 + 64 + e] = v;
        Sf[1024 + b * 128 + e] = ecC[(size_t)(b0 + b) * 64 + e];
    }
    __syncthreads();                                        // B7

    // MLP: wave-local per b = wave id, j = lane
    {
        const int b = t >> 6, j = t & 63;
        const float* x = Sf + 1024 + b * 128;
        {
            float a = bm1[j];
            const float* wr = Wm1 + j * 128;
#pragma unroll 8
            for (int k = 0; k < 128; ++k) a += x[k] * wr[k];
            Sf[2048 + b * 64 + j] = fmaxf(a, 0.f);
        }
        __syncthreads();                                    // B8
        if (j < 32) {
            float a = bm2[j];
            const float* wr = Wm2 + j * 64;
#pragma unroll 8
            for (int k = 0; k < 64; ++k) a += Sf[2048 + b * 64 + k] * wr[k];
            Sf[2560 + b * 32 + j] = fmaxf(a, 0.f);
        }
        __syncthreads();                                    // B9
        float p = (j < 32) ? Sf[2560 + b * 32 + j] * Wm3[j] : 0.f;
#pragma unroll
        for (int kk = 1; kk < 64; kk <<= 1) p += __shfl_xor(p, kk);
        if (j == 0) out[b0 + b] = p + bm3[0];
    }
}

extern "C" void kernel_launch(void* const* d_in, const int* in_sizes, int n_in,
                              void* d_out, int out_size, void* d_ws, size_t ws_size,
                              hipStream_t stream) {
    const float* cand  = (const float*)d_in[0];   // (8192,1000) fp32
    const float* rated = (const float*)d_in[1];   // (1000,1000)
    const float* um    = (const float*)d_in[2];   // (8192,1000)
    const float* We    = (const float*)d_in[3];   // (64,1000)
    const float* be    = (const float*)d_in[4];   // (64,)
    const float* Wa1   = (const float*)d_in[5];   // (16,128)
    const float* ba1   = (const float*)d_in[6];   // (16,)
    const float* Wa2   = (const float*)d_in[7];   // (1,16)
    // d_in[8] = ba2: softmax-invariant (exact), skipped
    const float* Wm1   = (const float*)d_in[9];   // (64,128)
    const float* bm1   = (const float*)d_in[10];  // (64,)
    const float* Wm2   = (const float*)d_in[11];  // (32,64)
    const float* bm2   = (const float*)d_in[12];  // (32,)
    const float* Wm3   = (const float*)d_in[13];  // (1,32)
    const float* bm3   = (const float*)d_in[14];  // (1,)

    // ws layout = 2,417,152 B — ceiling proven in-use since round 5.
    float* arw   = (float*)d_ws;                  // 16000 f
    float* ec    = arw + 16000;                   // 524288 f
    u16*   er_th = (u16*)(ec + 524288);           // 64000 u16
    u16*   er_tl = er_th + 64000;                 // 64000 u16
    float* out   = (float*)d_out;

    kemb_rated<<<dim3(63),   dim3(256), 0, stream>>>(rated, We, be, Wa1, er_th, er_tl, arw);
    kemb_mfma <<<dim3(512),  dim3(256), 0, stream>>>(cand, We, be, ec, 8192);
    k3v9      <<<dim3(1024), dim3(512), 0, stream>>>(arw, ec, er_th, er_tl, um,
                                                     Wa1, ba1, Wa2, Wm1, bm1,
                                                     Wm2, bm2, Wm3, bm3, out);
}

// Round 10
// 203.196 us; speedup vs baseline: 1.2912x; 1.1846x over previous
//
#include <hip/hip_runtime.h>

typedef unsigned short u16;
typedef unsigned int   u32;
typedef float f32x4  __attribute__((ext_vector_type(4)));
typedef short bf16x8 __attribute__((ext_vector_type(8)));

__device__ __forceinline__ u16 f2b_rne(float x) {
    u32 u = __float_as_uint(x);
    return (u16)((u + 0x7fffu + ((u >> 16) & 1u)) >> 16);
}
__device__ __forceinline__ float b2f(u16 u) { return __uint_as_float((u32)u << 16); }
__device__ __forceinline__ void split1(float x, u16& h, u16& l) {
    h = f2b_rne(x);
    l = f2b_rne(x - b2f(h));
}
__device__ __forceinline__ void mk_frag(f32x4 a, f32x4 b, bf16x8& hi, bf16x8& lo) {
#pragma unroll
    for (int j = 0; j < 4; ++j) { u16 h, l; split1(a[j], h, l); hi[j] = (short)h; lo[j] = (short)l; }
#pragma unroll
    for (int j = 0; j < 4; ++j) { u16 h, l; split1(b[j], h, l); hi[4+j] = (short)h; lo[4+j] = (short)l; }
}

// ---------------------------------------------------------------------------
// kemb_mfma (cand): ec[M x 64](fp32) = X @ We^T + be, split-bf16 MFMA.
// Verbatim from rounds 5-9 (proven PASS).
// ---------------------------------------------------------------------------
__global__ __launch_bounds__(256) void kemb_mfma(
    const float* __restrict__ X, const float* __restrict__ W, const float* __restrict__ be,
    float* __restrict__ out, int M)
{
    const int wv   = threadIdx.x >> 6;
    const int lane = threadIdx.x & 63;
    const int l15  = lane & 15;
    const int q    = lane >> 4;

    const int arow = min(blockIdx.x * 16 + l15, M - 1);
    const float* xr = X + (size_t)arow * 1000;
    const float* wr = W + (size_t)(wv * 16 + l15) * 1000;

    const float bias = be[wv * 16 + l15];
    f32x4 acc = {bias, bias, bias, bias};

    for (int kc = 0; kc < 992; kc += 32) {
        bf16x8 ah, al, bh, bl;
        mk_frag(*(const f32x4*)(xr + kc + q * 8), *(const f32x4*)(xr + kc + q * 8 + 4), ah, al);
        mk_frag(*(const f32x4*)(wr + kc + q * 8), *(const f32x4*)(wr + kc + q * 8 + 4), bh, bl);
        acc = __builtin_amdgcn_mfma_f32_16x16x32_bf16(ah, bh, acc, 0, 0, 0);
        acc = __builtin_amdgcn_mfma_f32_16x16x32_bf16(ah, bl, acc, 0, 0, 0);
        acc = __builtin_amdgcn_mfma_f32_16x16x32_bf16(al, bh, acc, 0, 0, 0);
    }
    {
        bf16x8 ah = {0,0,0,0,0,0,0,0}, al = {0,0,0,0,0,0,0,0};
        bf16x8 bh = {0,0,0,0,0,0,0,0}, bl = {0,0,0,0,0,0,0,0};
        if (q == 0) {
            mk_frag(*(const f32x4*)(xr + 992), *(const f32x4*)(xr + 996), ah, al);
            mk_frag(*(const f32x4*)(wr + 992), *(const f32x4*)(wr + 996), bh, bl);
        }
        acc = __builtin_amdgcn_mfma_f32_16x16x32_bf16(ah, bh, acc, 0, 0, 0);
        acc = __builtin_amdgcn_mfma_f32_16x16x32_bf16(ah, bl, acc, 0, 0, 0);
        acc = __builtin_amdgcn_mfma_f32_16x16x32_bf16(al, bh, acc, 0, 0, 0);
    }
#pragma unroll
    for (int r = 0; r < 4; ++r) {
        int m = blockIdx.x * 16 + q * 4 + r;
        if (m < M) out[(size_t)m * 64 + wv * 16 + l15] = acc[r];
    }
}

// ---------------------------------------------------------------------------
// kemb_rated: GEMM for rated (M=1000); emits er_t SINGLE bf16 (lo plane
// dropped — single-plane P2 this round) and ar via in-kernel MFMA.
// Grid 64: block 63 converts Wm1 -> bf16 in ws (for k3's MFMA MLP1).
// ---------------------------------------------------------------------------
__global__ __launch_bounds__(256) void kemb_rated(
    const float* __restrict__ X, const float* __restrict__ W, const float* __restrict__ be,
    const float* __restrict__ Wa1, const float* __restrict__ Wm1,
    u16* __restrict__ er_th, float* __restrict__ ar, u16* __restrict__ Wm1b)
{
    if (blockIdx.x == 63) {            // Wm1 (64x128) -> bf16 plane in ws
        for (int idx = threadIdx.x; idx < 8192; idx += 256)
            Wm1b[idx] = f2b_rne(Wm1[idx]);
        return;
    }
    __shared__ float smt[16 * 68];
    const int wv   = threadIdx.x >> 6;
    const int lane = threadIdx.x & 63;
    const int l15  = lane & 15;
    const int q    = lane >> 4;
    const int i0   = blockIdx.x * 16;

    const int arow = min(i0 + l15, 999);
    const float* xr = X + (size_t)arow * 1000;
    const float* wr = W + (size_t)(wv * 16 + l15) * 1000;

    const float bias = be[wv * 16 + l15];
    f32x4 acc = {bias, bias, bias, bias};

    for (int kc = 0; kc < 992; kc += 32) {
        bf16x8 ah, al, bh, bl;
        mk_frag(*(const f32x4*)(xr + kc + q * 8), *(const f32x4*)(xr + kc + q * 8 + 4), ah, al);
        mk_frag(*(const f32x4*)(wr + kc + q * 8), *(const f32x4*)(wr + kc + q * 8 + 4), bh, bl);
        acc = __builtin_amdgcn_mfma_f32_16x16x32_bf16(ah, bh, acc, 0, 0, 0);
        acc = __builtin_amdgcn_mfma_f32_16x16x32_bf16(ah, bl, acc, 0, 0, 0);
        acc = __builtin_amdgcn_mfma_f32_16x16x32_bf16(al, bh, acc, 0, 0, 0);
    }
    {
        bf16x8 ah = {0,0,0,0,0,0,0,0}, al = {0,0,0,0,0,0,0,0};
        bf16x8 bh = {0,0,0,0,0,0,0,0}, bl = {0,0,0,0,0,0,0,0};
        if (q == 0) {
            mk_frag(*(const f32x4*)(xr + 992), *(const f32x4*)(xr + 996), ah, al);
            mk_frag(*(const f32x4*)(wr + 992), *(const f32x4*)(wr + 996), bh, bl);
        }
        acc = __builtin_amdgcn_mfma_f32_16x16x32_bf16(ah, bh, acc, 0, 0, 0);
        acc = __builtin_amdgcn_mfma_f32_16x16x32_bf16(ah, bl, acc, 0, 0, 0);
        acc = __builtin_amdgcn_mfma_f32_16x16x32_bf16(al, bh, acc, 0, 0, 0);
    }

    const int e = wv * 16 + l15;
#pragma unroll
    for (int r = 0; r < 4; ++r) {
        int i = i0 + q * 4 + r;
        smt[(q * 4 + r) * 68 + e] = acc[r];
        if (i < 1000) er_th[(size_t)e * 1000 + i] = f2b_rne(acc[r]);
    }
    __syncthreads();

    if (wv == 0) {                      // ar = er @ W1r^T (split fp32-class)
        f32x4 a2 = {0.f, 0.f, 0.f, 0.f};
#pragma unroll
        for (int kc = 0; kc < 64; kc += 32) {
            const float* ap = smt + l15 * 68 + kc + q * 8;
            const float* bp = Wa1 + l15 * 128 + 64 + kc + q * 8;
            bf16x8 ah, al, bh, bl;
            mk_frag(*(const f32x4*)ap, *(const f32x4*)(ap + 4), ah, al);
            mk_frag(*(const f32x4*)bp, *(const f32x4*)(bp + 4), bh, bl);
            a2 = __builtin_amdgcn_mfma_f32_16x16x32_bf16(ah, bh, a2, 0, 0, 0);
            a2 = __builtin_amdgcn_mfma_f32_16x16x32_bf16(ah, bl, a2, 0, 0, 0);
            a2 = __builtin_amdgcn_mfma_f32_16x16x32_bf16(al, bh, a2, 0, 0, 0);
        }
#pragma unroll
        for (int r = 0; r < 4; ++r) {
            int i = i0 + q * 4 + r;
            if (i < 1000) ar[(size_t)i * 16 + l15] = a2[r];
        }
    }
}

// ---------------------------------------------------------------------------
// k3v10: 16 rows / 1024 threads / 512 blocks -> exactly 2 blocks/CU x 16
// waves = 32 waves/CU (100% occupancy; wave-cap config). Single-bf16 P/er:
// P2 is 1 MFMA per fragment; scores stored u16 bf16 IN PLACE (pitch 1032
// u16 -> 2-way banks on MFMA A-reads, free). MLP layer 1 on MFMA with
// ws-preconverted Wm1b (kills the 64-line/instr Wm1 scatter).
// LDS: S16 u16[16*1032] (33,024B; overlays as f32: PA[4][16][64] @0,
// PA2 @0 (after PA dead), H1 @f4096, H2 @f5120), ACL[256], SUMS[16],
// XB16 u16[16*136] (pad->2-way banks). Total 38.5 KB -> 2 blocks/CU.
// ---------------------------------------------------------------------------
__global__ __launch_bounds__(1024, 8) void k3v10(
    const float* __restrict__ ar, const float* __restrict__ ecC,
    const u16* __restrict__ er_th, const float* __restrict__ um,
    const float* __restrict__ Wa1, const float* __restrict__ ba1,
    const float* __restrict__ Wa2, const u16* __restrict__ Wm1b,
    const float* __restrict__ bm1,
    const float* __restrict__ Wm2, const float* __restrict__ bm2,
    const float* __restrict__ Wm3, const float* __restrict__ bm3,
    float* __restrict__ out)
{
    __shared__ u16   S16[16 * 1032];
    __shared__ float ACL[256];
    __shared__ float SUMS[16];
    __shared__ u16   XB16[16 * 136];
    float* Sf = (float*)S16;
    const int t  = threadIdx.x;
    const int b0 = blockIdx.x * 16;

    // P0: ACL[b][a] = ba1[a] + ec[b0+b] . W1c[a]
    if (t < 256) {
        const int a = t & 15, b = t >> 4;
        float acc = ba1[a];
        const float* ecr = ecC + (size_t)(b0 + b) * 64;
        const float* w = Wa1 + a * 128;
#pragma unroll 8
        for (int e = 0; e < 64; ++e) acc += ecr[e] * w[e];
        ACL[b * 16 + a] = acc;
    }
    __syncthreads();                                        // B1

    // P1: thread = item i; computes scores for all 16 b, writes u16 bf16.
    {
        const int i = t;
        if (i < 1000) {
            const f32x4* a4 = (const f32x4*)(ar + (size_t)i * 16);
            f32x4 r0 = a4[0], r1 = a4[1], r2 = a4[2], r3 = a4[3];
            float w2[16];
#pragma unroll
            for (int a = 0; a < 16; ++a) w2[a] = Wa2[a];
#pragma unroll 4
            for (int b = 0; b < 16; ++b) {
                const f32x4* ac4 = (const f32x4*)(ACL + b * 16);
                f32x4 c0 = ac4[0], c1 = ac4[1], c2 = ac4[2], c3 = ac4[3];
                float s0 = 0.f, s1 = 0.f;
                s0 += fmaxf(c0[0] + r0[0], 0.f) * w2[0];
                s1 += fmaxf(c0[1] + r0[1], 0.f) * w2[1];
                s0 += fmaxf(c0[2] + r0[2], 0.f) * w2[2];
                s1 += fmaxf(c0[3] + r0[3], 0.f) * w2[3];
                s0 += fmaxf(c1[0] + r1[0], 0.f) * w2[4];
                s1 += fmaxf(c1[1] + r1[1], 0.f) * w2[5];
                s0 += fmaxf(c1[2] + r1[2], 0.f) * w2[6];
                s1 += fmaxf(c1[3] + r1[3], 0.f) * w2[7];
                s0 += fmaxf(c2[0] + r2[0], 0.f) * w2[8];
                s1 += fmaxf(c2[1] + r2[1], 0.f) * w2[9];
                s0 += fmaxf(c2[2] + r2[2], 0.f) * w2[10];
                s1 += fmaxf(c2[3] + r2[3], 0.f) * w2[11];
                s0 += fmaxf(c3[0] + r3[0], 0.f) * w2[12];
                s1 += fmaxf(c3[1] + r3[1], 0.f) * w2[13];
                s0 += fmaxf(c3[2] + r3[2], 0.f) * w2[14];
                s1 += fmaxf(c3[3] + r3[3], 0.f) * w2[15];
                S16[b * 1032 + i] = f2b_rne(s0 + s1);
            }
        }
    }
    __syncthreads();                                        // B2

    // softmax: wave b (16 waves <-> 16 rows). In-place u16 -> u16 (per-lane
    // slots, no cross-lane hazard -> no extra barrier).
    {
        const int b = t >> 6, g = t & 63;
        float sv[16], uv[16];
#pragma unroll
        for (int k = 0; k < 16; ++k) {
            int i = g + 64 * k;
            sv[k] = (i < 1000) ? b2f(S16[b * 1032 + i]) : -1e30f;
        }
        float m = -1e30f;
#pragma unroll
        for (int k = 0; k < 16; ++k) m = fmaxf(m, sv[k]);
#pragma unroll
        for (int k = 1; k < 64; k <<= 1) m = fmaxf(m, __shfl_xor(m, k));
        const float* umr = um + (size_t)(b0 + b) * 1000;
#pragma unroll
        for (int k = 0; k < 16; ++k) {
            int i = g + 64 * k;
            uv[k] = (i < 1000) ? umr[i] : 0.f;
        }
        float sum = 0.f;
#pragma unroll
        for (int k = 0; k < 16; ++k) {
            int i = g + 64 * k;
            if (i < 1000) {
                float w = __expf(sv[k] - m);
                sum += w;
                S16[b * 1032 + i] = f2b_rne(w * uv[k]);     // P plane in place
            }
        }
#pragma unroll
        for (int k = 1; k < 64; k <<= 1) sum += __shfl_xor(sum, k);
        if (g == 0) SUMS[b] = 1.0f / sum;
    }
    __syncthreads();                                        // B3

    // P2: user_emb = P @ er^T via single-bf16 MFMA. wave wv: e-tile = wv&3,
    // K-quarter = wv>>2. A rows m = l15 = the 16 real batch rows.
    {
        const int wv = t >> 6, lane = t & 63, l15 = lane & 15, q = lane >> 4;
        const int et = wv & 3, h = wv >> 2;
        const u16* php = S16 + l15 * 1032;
        const u16* bhp = er_th + (size_t)(et * 16 + l15) * 1000;
        f32x4 acc = {0.f, 0.f, 0.f, 0.f};

        const int kc0 = h * 256;
        const int kc1 = (h == 3) ? 992 : kc0 + 256;
        for (int kc = kc0; kc < kc1; kc += 32) {
            bf16x8 ah = *(const bf16x8*)(php + kc + q * 8);
            bf16x8 bh = *(const bf16x8*)(bhp + kc + q * 8);
            acc = __builtin_amdgcn_mfma_f32_16x16x32_bf16(ah, bh, acc, 0, 0, 0);
        }
        if (h == 3) {                   // K tail 992..999 (q==0 live)
            bf16x8 ah = {0,0,0,0,0,0,0,0}, bh = {0,0,0,0,0,0,0,0};
            if (q == 0) {
                ah = *(const bf16x8*)(php + 992);
                bh = *(const bf16x8*)(bhp + 992);
            }
            acc = __builtin_amdgcn_mfma_f32_16x16x32_bf16(ah, bh, acc, 0, 0, 0);
        }
        __syncthreads();                                    // B4: all P reads done
        // D[m = q*4+r][e-col = l15] -> PA[h][m][et*16+l15]
#pragma unroll
        for (int r = 0; r < 4; ++r)
            Sf[h * 1024 + (q * 4 + r) * 64 + et * 16 + l15] = acc[r];
    }
    __syncthreads();                                        // B5

    // P2b: combine K-quarters, scale, build x = [ec | user_emb] as bf16
    {
        const int b = t >> 6, e = t & 63;
        float v = (Sf[b * 64 + e] + Sf[1024 + b * 64 + e]
                 + Sf[2048 + b * 64 + e] + Sf[3072 + b * 64 + e]) * SUMS[b];
        XB16[b * 136 + 64 + e] = f2b_rne(v);
        XB16[b * 136 + e] = f2b_rne(ecC[(size_t)(b0 + b) * 64 + e]);
    }
    __syncthreads();                                        // B6

    // MLP layer 1 via MFMA: h1 = relu(x @ Wm1^T + bm1). wave wv: n-tile =
    // wv&3, K-quarter(32) = wv>>2. A = XB16 (pitch 136 -> 2-way banks).
    {
        const int wv = t >> 6, lane = t & 63, l15 = lane & 15, q = lane >> 4;
        const int nt = wv & 3, kh = wv >> 2;
        bf16x8 ah = *(const bf16x8*)(XB16 + l15 * 136 + kh * 32 + q * 8);
        bf16x8 bh = *(const bf16x8*)(Wm1b + (size_t)(nt * 16 + l15) * 128 + kh * 32 + q * 8);
        f32x4 acc = {0.f, 0.f, 0.f, 0.f};
        acc = __builtin_amdgcn_mfma_f32_16x16x32_bf16(ah, bh, acc, 0, 0, 0);
        // PA region dead (read at B6) -> PA2[kh][m][nt*16+l15]
#pragma unroll
        for (int r = 0; r < 4; ++r)
            Sf[kh * 1024 + (q * 4 + r) * 64 + nt * 16 + l15] = acc[r];
    }
    __syncthreads();                                        // B7

    // reduce + bias + relu -> H1 (f32 @ f-idx 4096)
    {
        const int b = t >> 6, o = t & 63;
        float a = bm1[o] + Sf[b * 64 + o] + Sf[1024 + b * 64 + o]
                + Sf[2048 + b * 64 + o] + Sf[3072 + b * 64 + o];
        Sf[4096 + b * 64 + o] = fmaxf(a, 0.f);
    }
    __syncthreads();                                        // B8

    // MLP layer 2 (64->32): wave b, lane j<32
    {
        const int b = t >> 6, j = t & 63;
        if (j < 32) {
            float a = bm2[j];
            const float* wr = Wm2 + j * 64;
            const float* x = Sf + 4096 + b * 64;
#pragma unroll 8
            for (int k = 0; k < 64; ++k) a += x[k] * wr[k];
            Sf[5120 + b * 32 + j] = fmaxf(a, 0.f);
        }
    }
    __syncthreads();                                        // B9

    // MLP layer 3 (32->1): wave b reduce
    {
        const int b = t >> 6, j = t & 63;
        float p = (j < 32) ? Sf[5120 + b * 32 + j] * Wm3[j] : 0.f;
#pragma unroll
        for (int kk = 1; kk < 64; kk <<= 1) p += __shfl_xor(p, kk);
        if (j == 0) out[b0 + b] = p + bm3[0];
    }
}

extern "C" void kernel_launch(void* const* d_in, const int* in_sizes, int n_in,
                              void* d_out, int out_size, void* d_ws, size_t ws_size,
                              hipStream_t stream) {
    const float* cand  = (const float*)d_in[0];   // (8192,1000) fp32
    const float* rated = (const float*)d_in[1];   // (1000,1000)
    const float* um    = (const float*)d_in[2];   // (8192,1000)
    const float* We    = (const float*)d_in[3];   // (64,1000)
    const float* be    = (const float*)d_in[4];   // (64,)
    const float* Wa1   = (const float*)d_in[5];   // (16,128)
    const float* ba1   = (const float*)d_in[6];   // (16,)
    const float* Wa2   = (const float*)d_in[7];   // (1,16)
    // d_in[8] = ba2: softmax-invariant (exact), skipped
    const float* Wm1   = (const float*)d_in[9];   // (64,128)
    const float* bm1   = (const float*)d_in[10];  // (64,)
    const float* Wm2   = (const float*)d_in[11];  // (32,64)
    const float* bm2   = (const float*)d_in[12];  // (32,)
    const float* Wm3   = (const float*)d_in[13];  // (1,32)
    const float* bm3   = (const float*)d_in[14];  // (1,)

    // ws: ar 64,000 + ec 2,097,152 + er_th 128,000 + Wm1b 16,384
    //   = 2,305,536 B <= 2,417,152 B (ceiling proven in-use since round 5).
    float* arw   = (float*)d_ws;                  // 16000 f
    float* ec    = arw + 16000;                   // 524288 f
    u16*   er_th = (u16*)(ec + 524288);           // 64000 u16
    u16*   wm1b  = er_th + 64000;                 // 8192 u16
    float* out   = (float*)d_out;

    kemb_rated<<<dim3(64),  dim3(256), 0, stream>>>(rated, We, be, Wa1, Wm1,
                                                    er_th, arw, wm1b);
    kemb_mfma <<<dim3(512), dim3(256), 0, stream>>>(cand, We, be, ec, 8192);
    k3v10     <<<dim3(512), dim3(1024), 0, stream>>>(arw, ec, er_th, um,
                                                     Wa1, ba1, Wa2, wm1b, bm1,
                                                     Wm2, bm2, Wm3, bm3, out);
}